// Round 3
// baseline (123.666 us; speedup 1.0000x reference)
//
#include <hip/hip_runtime.h>

// HausdorffLoss (average): B=8, N=M=4096, C=128, fp32 in/out.
// R11: occupancy unlock. R10's LDS_Block_Size was 41984 B -> floor(163840/
// 41984) = 3 blocks/CU, so the 1024-block grid ran as 768 + 256-straggler
// rounds at ~19% avg occupancy (latency-bound: 40% of cycles in neither
// pipe). We are 1024 B over the 4-blocks/CU boundary (40960):
//   - rowmax_lds[2][128] (1 KB) is only live AFTER the K-loop, and B_lds[0]
//     is provably dead by then (last reads in iter 14, ordered before the
//     top-of-iter-15 barrier; iter 15 reads only B_lds[1], stages nothing).
//     -> alias rowmax onto B_lds[0]. LDS = 40960 -> 4 blocks/CU, one clean
//     dispatch round (1024 = 256 CUs x 4), 4 waves/SIMD latency cover.
//   - colmax_lds[rh][col] is written exactly once per block (each panel col
//     belongs to exactly one iteration) -> drop the -1e30 init loop and the
//     fmax read-modify-write; plain store.
// Keeps R10's e-trick (prep stores -0.5*||x||^2; acc init ha+hb so
// acc = -d^2/2; min d^2 == -2*max e) and R8's coalesced gl2lds staging.
#define B_ 8
#define N_ 4096
#define M_ 4096
#define C_ 128
#define BN_ (B_ * N_)
#define BM_ (B_ * M_)

typedef __attribute__((ext_vector_type(8))) short bf16x8;    // MFMA A/B frag
typedef __attribute__((ext_vector_type(4))) float floatx4;   // MFMA C/D frag
typedef __attribute__((ext_vector_type(8))) unsigned short ushort8;

// fp32 -> bf16 round-to-nearest-even
__device__ __forceinline__ unsigned short f2bf(float x) {
    unsigned int u = __float_as_uint(x);
    u += 0x7FFFu + ((u >> 16) & 1u);
    return (unsigned short)(u >> 16);
}

// async global->LDS, 16 B per lane; LDS dest = wave-uniform base + lane*16
__device__ __forceinline__ void gl2lds16(const void* g, void* l) {
    __builtin_amdgcn_global_load_lds(
        (const __attribute__((address_space(1))) void*)g,
        (__attribute__((address_space(3))) void*)l, 16, 0, 0);
}

// ---------------------------------------------------------------------------
// Prep: bf16 convert (swizzled: ws[row][g ^ (row&15)] = src[row][g]),
// norms[row] = -0.5 * ||row||^2 (fp32, pre-scaled for the e-trick), out zero.
// Wave handles 4 rows: lane = (row_in_4 : 2, k-group : 4).
// Grid = (BN_+BM_)/16 = 4096 blocks x 256 threads.
// ---------------------------------------------------------------------------
__global__ __launch_bounds__(256) void prep_kernel(
    const float* __restrict__ S1, const float* __restrict__ S2,
    float* __restrict__ norms, unsigned short* __restrict__ bfA,
    unsigned short* __restrict__ bfB, float* __restrict__ out) {
    const int lane = threadIdx.x & 63;
    const int w    = threadIdx.x >> 6;
    const int gw   = blockIdx.x * 4 + w;
    const int r4   = lane >> 4;
    const int g4   = lane & 15;
    const int row  = gw * 4 + r4;          // 0 .. BN_+BM_-1

    const float* src = (row < BN_) ? S1 + (size_t)row * C_
                                   : S2 + (size_t)(row - BN_) * C_;
    float4 v0 = ((const float4*)src)[g4 * 2];
    float4 v1 = ((const float4*)src)[g4 * 2 + 1];

    float s = v0.x*v0.x + v0.y*v0.y + v0.z*v0.z + v0.w*v0.w
            + v1.x*v1.x + v1.y*v1.y + v1.z*v1.z + v1.w*v1.w;
    s += __shfl_xor(s, 1, 64);
    s += __shfl_xor(s, 2, 64);
    s += __shfl_xor(s, 4, 64);
    s += __shfl_xor(s, 8, 64);

    ushort8 o;
    o[0] = f2bf(v0.x); o[1] = f2bf(v0.y); o[2] = f2bf(v0.z); o[3] = f2bf(v0.w);
    o[4] = f2bf(v1.x); o[5] = f2bf(v1.y); o[6] = f2bf(v1.z); o[7] = f2bf(v1.w);

    unsigned short* dst = (row < BN_) ? bfA + (size_t)row * C_
                                      : bfB + (size_t)(row - BN_) * C_;
    *(ushort8*)&dst[(g4 ^ (row & 15)) * 8] = o;

    if (g4 == 0) norms[row] = -0.5f * s;
    if (blockIdx.x == 0 && threadIdx.x < B_) out[threadIdx.x] = 0.f;
}

// ---------------------------------------------------------------------------
// Main: grid (N/128, M/1024, B). 4 waves; wave tile = 64 rows x 32 cols.
// LDS: two 16 KB buffers (A tile pre-loop, then double-buffered B tiles) +
// colmax[2][1024]. rowmax[2][128] aliases B_lds[0] (dead after the loop).
// Total 40960 B -> 4 blocks/CU.
// ---------------------------------------------------------------------------
__global__ __launch_bounds__(256, 2) void hausdorff_mfma(
    const unsigned short* __restrict__ Abf, const unsigned short* __restrict__ Bbf,
    const float* __restrict__ ahalf_g, const float* __restrict__ bhalf_g,
    float* __restrict__ rowpart, float* __restrict__ colpart) {

    __shared__ unsigned short B_lds[2][64 * 128];   // 2 x 16 KB
    __shared__ float colmax_lds[2][1024];           // 8 KB [row-half][col]

    const int b     = blockIdx.z;
    const int row0  = blockIdx.x * 128;
    const int panel = blockIdx.y;                   // cols panel*1024 ..
    const int tid   = threadIdx.x;
    const int lane  = tid & 63;
    const int w     = tid >> 6;
    const int lm    = lane & 15;
    const int quad  = lane >> 4;
    const int wrow  = (w >> 1) * 64;                // wave's row half
    const int qc    = (w & 1) * 32;                 // wave's col half (of 64)
    const int rh    = w >> 1;                       // colmax slot owner
    const int ch    = w & 1;                        // rowmax slot owner

    const unsigned short* Aws = Abf + ((size_t)b * N_ + row0) * C_;
    const unsigned short* Bws = Bbf + ((size_t)b * M_ + (size_t)panel * 1024) * C_;
    const float* bhalf = bhalf_g + (size_t)b * M_ + panel * 1024;

    // ---- stage A through both buffers: rows 0-63 -> buf0, 64-127 -> buf1
    #pragma unroll
    for (int k = 0; k < 4; ++k) {
        const int off = w * 2048 + k * 512;         // ushorts
        gl2lds16(Aws + off + lane * 8,        &B_lds[0][off]);
        gl2lds16(Aws + 8192 + off + lane * 8, &B_lds[1][off]);
    }

    // -0.5*||a||^2 for this lane's 16 rows: wrow + 16i + 4*quad + reg
    float ha[16];
    #pragma unroll
    for (int i = 0; i < 4; ++i) {
        float4 t = *(const float4*)&ahalf_g[(size_t)b * N_ + row0 + wrow + 16 * i + 4 * quad];
        ha[4*i+0] = t.x; ha[4*i+1] = t.y; ha[4*i+2] = t.z; ha[4*i+3] = t.w;
    }

    float rv[16];                                   // running e-max per row
    #pragma unroll
    for (int v = 0; v < 16; ++v) rv[v] = -1e30f;

    __syncthreads();   // A staged

    // A fragments once; waves 0,1 from buf0 (rows 0-63), waves 2,3 from buf1
    bf16x8 af[4][4];
    {
        const unsigned short* Abuf = &B_lds[w >> 1][0];
        #pragma unroll
        for (int i = 0; i < 4; ++i)
            #pragma unroll
            for (int c = 0; c < 4; ++c)
                af[i][c] = *(const bf16x8*)
                    &Abuf[(16 * i + lm) * 128 + (((c * 4 + quad) ^ lm) * 8)];
    }

    __syncthreads();   // all af reads done -> buffers reusable

    // stage B tile 0 into buf0
    #pragma unroll
    for (int k = 0; k < 4; ++k) {
        const int off = w * 2048 + k * 512;
        gl2lds16(Bws + off + lane * 8, &B_lds[0][off]);
    }

    for (int it = 0; it < 16; ++it) {
        const int cur = it & 1;
        __syncthreads();   // tile `it` staged (its loads a full iter old)

        if (it < 15) {     // stage next tile into the other buffer
            const unsigned short* Bt = Bws + (size_t)(it + 1) * 64 * C_;
            #pragma unroll
            for (int k = 0; k < 4; ++k) {
                const int off = w * 2048 + k * 512;
                gl2lds16(Bt + off + lane * 8, &B_lds[cur ^ 1][off]);
            }
        }
        const float hb0 = bhalf[it * 64 + qc + lm];
        const float hb1 = bhalf[it * 64 + qc + 16 + lm];

        bf16x8 bf[2][4];
        #pragma unroll
        for (int j = 0; j < 2; ++j)
            #pragma unroll
            for (int c = 0; c < 4; ++c)
                bf[j][c] = *(const bf16x8*)
                    &B_lds[cur][(qc + 16 * j + lm) * 128 + (((c * 4 + quad) ^ lm) * 8)];

        // acc init = ha + hb  ->  acc accumulates to  inner - (sa+sb)/2
        floatx4 acc[4][2];
        #pragma unroll
        for (int i = 0; i < 4; ++i)
            #pragma unroll
            for (int r = 0; r < 4; ++r) {
                acc[i][0][r] = ha[4 * i + r] + hb0;
                acc[i][1][r] = ha[4 * i + r] + hb1;
            }
        #pragma unroll
        for (int c = 0; c < 4; ++c)
            #pragma unroll
            for (int i = 0; i < 4; ++i)
                #pragma unroll
                for (int j = 0; j < 2; ++j)
                    acc[i][j] = __builtin_amdgcn_mfma_f32_16x16x32_bf16(
                        af[i][c], bf[j][c], acc[i][j], 0, 0, 0);

        // pure max epilogue (min d^2 == -2 * max e)
        float cv0a = -1e30f, cv0b = -1e30f, cv1a = -1e30f, cv1b = -1e30f;
        #pragma unroll
        for (int i = 0; i < 4; ++i) {
            #pragma unroll
            for (int r = 0; r < 4; ++r)
                rv[4 * i + r] = fmaxf(rv[4 * i + r],
                                      fmaxf(acc[i][0][r], acc[i][1][r]));  // v_max3
            float m0 = fmaxf(fmaxf(acc[i][0][0], acc[i][0][1]),
                             fmaxf(acc[i][0][2], acc[i][0][3]));
            float m1 = fmaxf(fmaxf(acc[i][1][0], acc[i][1][1]),
                             fmaxf(acc[i][1][2], acc[i][1][3]));
            if (i & 1) { cv0b = fmaxf(cv0b, m0); cv1b = fmaxf(cv1b, m1); }
            else       { cv0a = fmaxf(cv0a, m0); cv1a = fmaxf(cv1a, m1); }
        }
        float cv0 = fmaxf(cv0a, cv0b), cv1 = fmaxf(cv1a, cv1b);
        cv0 = fmaxf(cv0, __shfl_xor(cv0, 16, 64));
        cv0 = fmaxf(cv0, __shfl_xor(cv0, 32, 64));
        cv1 = fmaxf(cv1, __shfl_xor(cv1, 16, 64));
        cv1 = fmaxf(cv1, __shfl_xor(cv1, 32, 64));
        if (quad == 0) {
            // each (rh, col) slot is written exactly once per block
            const int c0 = it * 64 + qc + lm;
            colmax_lds[rh][c0]      = cv0;
            colmax_lds[rh][c0 + 16] = cv1;
        }
    }

    // row maxes: butterfly across the 16 lane-cols, then stash per col-half.
    // rowmax aliases B_lds[0]: dead since iter 14 (reads ordered before the
    // top-of-iter-15 barrier; iter 15 reads only B_lds[1], stages nothing).
    float* rowmax_lds = (float*)&B_lds[0][0];       // [2][128] aliased
    #pragma unroll
    for (int s = 1; s < 16; s <<= 1)
        #pragma unroll
        for (int v = 0; v < 16; ++v)
            rv[v] = fmaxf(rv[v], __shfl_xor(rv[v], s, 64));
    if (lm == 0) {
        #pragma unroll
        for (int v = 0; v < 16; ++v)
            rowmax_lds[ch * 128 + wrow + 16 * (v >> 2) + 4 * quad + (v & 3)] = rv[v];
    }

    __syncthreads();

    // flush col partials: combine row halves, plain coalesced stores
    #pragma unroll
    for (int k = 0; k < 4; ++k) {
        const int c = tid + 256 * k;
        colpart[((size_t)blockIdx.x * B_ + b) * M_ + (size_t)panel * 1024 + c] =
            fmaxf(colmax_lds[0][c], colmax_lds[1][c]);
    }
    // flush row partials: combine col halves
    if (tid < 128)
        rowpart[((size_t)panel * B_ + b) * N_ + row0 + tid] =
            fmaxf(rowmax_lds[tid], rowmax_lds[128 + tid]);
}

// ---------------------------------------------------------------------------
// Reduce: 64 blocks (8 per batch). rows: max-e over 4 panel partials;
// cols: max-e over 32 row-block partials; d^2 = max(-2e, 0); sqrt-mean.
// ---------------------------------------------------------------------------
__global__ __launch_bounds__(256) void hausdorff_reduce(
    const float* __restrict__ rowpart, const float* __restrict__ colpart,
    float* __restrict__ out) {
    __shared__ float ws4[4];
    const int b    = blockIdx.x >> 3;
    const int part = blockIdx.x & 7;
    const int base = part * 512;
    float s = 0.f;
    for (int i = base + (int)threadIdx.x; i < base + 512; i += 256) {
        float ra = fmaxf(rowpart[((size_t)0 * B_ + b) * N_ + i],
                         rowpart[((size_t)1 * B_ + b) * N_ + i]);
        float rb = fmaxf(rowpart[((size_t)2 * B_ + b) * N_ + i],
                         rowpart[((size_t)3 * B_ + b) * N_ + i]);
        float rm = fmaxf(ra, rb);
        float ca = -1e30f, cb = -1e30f;
        #pragma unroll
        for (int x = 0; x < 32; x += 2) {
            ca = fmaxf(ca, colpart[((size_t)x * B_ + b) * M_ + i]);
            cb = fmaxf(cb, colpart[((size_t)(x + 1) * B_ + b) * M_ + i]);
        }
        float cm = fmaxf(ca, cb);
        s += sqrtf(fmaxf(-2.f * rm, 0.f)) * (1.f / N_)
           + sqrtf(fmaxf(-2.f * cm, 0.f)) * (1.f / M_);
    }
    #pragma unroll
    for (int off = 32; off > 0; off >>= 1) s += __shfl_down(s, off, 64);
    if ((threadIdx.x & 63) == 0) ws4[threadIdx.x >> 6] = s;
    __syncthreads();
    if (threadIdx.x == 0)
        atomicAdd(&out[b], ws4[0] + ws4[1] + ws4[2] + ws4[3]);
}

extern "C" void kernel_launch(void* const* d_in, const int* in_sizes, int n_in,
                              void* d_out, int out_size, void* d_ws, size_t ws_size,
                              hipStream_t stream) {
    const float* s1 = (const float*)d_in[0];
    const float* s2 = (const float*)d_in[1];
    float* out = (float*)d_out;

    // ws: norms(BN+BM f32, pre-scaled -0.5x) | bfA | bfB | rowpart | colpart
    float* norms         = (float*)d_ws;
    unsigned short* bfA  = (unsigned short*)(norms + BN_ + BM_);
    unsigned short* bfB  = bfA + (size_t)BN_ * C_;
    float* rowpart       = (float*)(bfB + (size_t)BM_ * C_);
    float* colpart       = rowpart + (size_t)4 * B_ * N_;

    prep_kernel<<<(BN_ + BM_) / 16, 256, 0, stream>>>(
        s1, s2, norms, bfA, bfB, out);

    dim3 grid(N_ / 128, M_ / 1024, B_);
    hausdorff_mfma<<<grid, 256, 0, stream>>>(
        bfA, bfB, norms, norms + BN_, rowpart, colpart);

    hausdorff_reduce<<<B_ * 8, 256, 0, stream>>>(rowpart, colpart, out);
}

// Round 6
// 121.371 us; speedup vs baseline: 1.0189x; 1.0189x over previous
//
#include <hip/hip_runtime.h>

// HausdorffLoss (average): B=8, N=M=4096, C=128, fp32 in/out.
// R13 (resubmit after infra failure; no result came back last round).
// Bigger tile = more MFMA per staged byte. R12's cooperative launch
// silently never ran (output stayed memset-zero) -> back to plain 3-kernel
// structure. R11 proved blocks/CU isn't the limiter; the ~45% dead cycles
// are the per-iteration critical path: 16KB gl2lds staging + barrier drain
// vs only 32 MFMA/wave. Retile: block = 256 rows x 1024-col panel, grid
// (16,4,8) = 512 = one clean 2-blocks/CU round. Each of 4 waves owns 64
// rows x ALL 64 cols of each B tile -> 64 MFMA/wave per 16KB staged tile
// (2x R10) and HALF the total B staging traffic (16 x-blocks, not 32).
//   - A fragments: one-time direct global->reg (R9 proved this part fine).
//   - bf regs in two j-halves: af 64 + acc 64 + bf 32 regs -> ~215 < 256.
//   - colmax_lds[4][1024]: per-wave-exclusive rows, plain stores, no init.
//   - rowpart: waves own disjoint rows -> direct global stores, no combine.
// Keeps: e-trick (norms = -0.5||x||^2, acc init ha+hb, min d2 = -2 max e),
// coalesced gl2lds B staging, single barrier per K-iter, atomic-free.
#define B_ 8
#define N_ 4096
#define M_ 4096
#define C_ 128
#define BN_ (B_ * N_)
#define BM_ (B_ * M_)

typedef __attribute__((ext_vector_type(8))) short bf16x8;    // MFMA A/B frag
typedef __attribute__((ext_vector_type(4))) float floatx4;   // MFMA C/D frag
typedef __attribute__((ext_vector_type(8))) unsigned short ushort8;

// fp32 -> bf16 round-to-nearest-even
__device__ __forceinline__ unsigned short f2bf(float x) {
    unsigned int u = __float_as_uint(x);
    u += 0x7FFFu + ((u >> 16) & 1u);
    return (unsigned short)(u >> 16);
}

// async global->LDS, 16 B per lane; LDS dest = wave-uniform base + lane*16
__device__ __forceinline__ void gl2lds16(const void* g, void* l) {
    __builtin_amdgcn_global_load_lds(
        (const __attribute__((address_space(1))) void*)g,
        (__attribute__((address_space(3))) void*)l, 16, 0, 0);
}

// ---------------------------------------------------------------------------
// Prep: bf16 convert (swizzled: ws[row][g ^ (row&15)] = src[row][g]),
// norms[row] = -0.5 * ||row||^2 (fp32, pre-scaled for the e-trick), out zero.
// Wave handles 4 rows: lane = (row_in_4 : 2, k-group : 4).
// Grid = (BN_+BM_)/16 = 4096 blocks x 256 threads.
// ---------------------------------------------------------------------------
__global__ __launch_bounds__(256) void prep_kernel(
    const float* __restrict__ S1, const float* __restrict__ S2,
    float* __restrict__ norms, unsigned short* __restrict__ bfA,
    unsigned short* __restrict__ bfB, float* __restrict__ out) {
    const int lane = threadIdx.x & 63;
    const int w    = threadIdx.x >> 6;
    const int gw   = blockIdx.x * 4 + w;
    const int r4   = lane >> 4;
    const int g4   = lane & 15;
    const int row  = gw * 4 + r4;          // 0 .. BN_+BM_-1

    const float* src = (row < BN_) ? S1 + (size_t)row * C_
                                   : S2 + (size_t)(row - BN_) * C_;
    float4 v0 = ((const float4*)src)[g4 * 2];
    float4 v1 = ((const float4*)src)[g4 * 2 + 1];

    float s = v0.x*v0.x + v0.y*v0.y + v0.z*v0.z + v0.w*v0.w
            + v1.x*v1.x + v1.y*v1.y + v1.z*v1.z + v1.w*v1.w;
    s += __shfl_xor(s, 1, 64);
    s += __shfl_xor(s, 2, 64);
    s += __shfl_xor(s, 4, 64);
    s += __shfl_xor(s, 8, 64);

    ushort8 o;
    o[0] = f2bf(v0.x); o[1] = f2bf(v0.y); o[2] = f2bf(v0.z); o[3] = f2bf(v0.w);
    o[4] = f2bf(v1.x); o[5] = f2bf(v1.y); o[6] = f2bf(v1.z); o[7] = f2bf(v1.w);

    unsigned short* dst = (row < BN_) ? bfA + (size_t)row * C_
                                      : bfB + (size_t)(row - BN_) * C_;
    *(ushort8*)&dst[(g4 ^ (row & 15)) * 8] = o;

    if (g4 == 0) norms[row] = -0.5f * s;
    if (blockIdx.x == 0 && threadIdx.x < B_) out[threadIdx.x] = 0.f;
}

// ---------------------------------------------------------------------------
// Main: grid (N/256, M/1024, B). 4 waves; wave = 64 rows x all 64 tile cols.
// LDS: 2 x 16 KB double-buffered B tiles + colmax[4][1024] = 48 KB.
// ---------------------------------------------------------------------------
__global__ __launch_bounds__(256, 2) void hausdorff_mfma(
    const unsigned short* __restrict__ Abf, const unsigned short* __restrict__ Bbf,
    const float* __restrict__ ahalf_g, const float* __restrict__ bhalf_g,
    float* __restrict__ rowpart, float* __restrict__ colpart) {

    __shared__ unsigned short B_lds[2][64 * 128];   // 2 x 16 KB
    __shared__ float colmax_lds[4][1024];           // 16 KB, wave-exclusive

    const int b     = blockIdx.z;
    const int x     = blockIdx.x;
    const int panel = blockIdx.y;                   // cols panel*1024 ..
    const int row0  = x * 256;
    const int tid   = threadIdx.x;
    const int lane  = tid & 63;
    const int w     = tid >> 6;
    const int lm    = lane & 15;
    const int quad  = lane >> 4;
    const int wrow  = w * 64;                       // wave's 64-row slice

    const unsigned short* Aws = Abf + ((size_t)b * N_ + row0 + wrow) * C_;
    const unsigned short* Bws = Bbf + ((size_t)b * M_ + (size_t)panel * 1024) * C_;
    const float* bhalf = bhalf_g + (size_t)b * M_ + panel * 1024;

    // A fragments: one-time direct global->reg. Swizzle cancels:
    // (row0 + wrow + 16i + lm) & 15 == lm  (row0, wrow multiples of 16).
    bf16x8 af[4][4];
    #pragma unroll
    for (int i = 0; i < 4; ++i)
        #pragma unroll
        for (int c = 0; c < 4; ++c)
            af[i][c] = *(const bf16x8*)
                &Aws[(16 * i + lm) * 128 + (((c * 4 + quad) ^ lm) * 8)];

    // -0.5*||a||^2 for this lane's 16 rows: wrow + 16i + 4*quad + r
    float ha[16];
    #pragma unroll
    for (int i = 0; i < 4; ++i) {
        float4 t = *(const float4*)&ahalf_g[(size_t)b * N_ + row0 + wrow + 16 * i + 4 * quad];
        ha[4*i+0] = t.x; ha[4*i+1] = t.y; ha[4*i+2] = t.z; ha[4*i+3] = t.w;
    }

    float rv[16];                                   // running e-max per row
    #pragma unroll
    for (int v = 0; v < 16; ++v) rv[v] = -1e30f;

    // stage B tile 0 into buf0 (16 KB: 4 waves x 4 gl2lds)
    #pragma unroll
    for (int k = 0; k < 4; ++k) {
        const int off = w * 2048 + k * 512;
        gl2lds16(Bws + off + lane * 8, &B_lds[0][off]);
    }

    for (int it = 0; it < 16; ++it) {
        const int cur = it & 1;
        __syncthreads();   // tile `it` staged (its loads a full iter old)

        if (it < 15) {     // stage next tile into the other buffer
            const unsigned short* Bt = Bws + (size_t)(it + 1) * 64 * C_;
            #pragma unroll
            for (int k = 0; k < 4; ++k) {
                const int off = w * 2048 + k * 512;
                gl2lds16(Bt + off + lane * 8, &B_lds[cur ^ 1][off]);
            }
        }

        float hb[4];
        #pragma unroll
        for (int j = 0; j < 4; ++j)
            hb[j] = bhalf[it * 64 + 16 * j + lm];

        // acc init = ha + hb  ->  acc accumulates to  inner - (sa+sb)/2
        floatx4 acc[4][4];
        #pragma unroll
        for (int i = 0; i < 4; ++i)
            #pragma unroll
            for (int j = 0; j < 4; ++j)
                #pragma unroll
                for (int r = 0; r < 4; ++r)
                    acc[i][j][r] = ha[4 * i + r] + hb[j];

        // two j-halves to cap bf register pressure (32 regs, reused)
        #pragma unroll
        for (int h = 0; h < 2; ++h) {
            bf16x8 bfr[2][4];
            #pragma unroll
            for (int j2 = 0; j2 < 2; ++j2)
                #pragma unroll
                for (int c = 0; c < 4; ++c)
                    bfr[j2][c] = *(const bf16x8*)
                        &B_lds[cur][(16 * (2 * h + j2) + lm) * 128 +
                                    (((c * 4 + quad) ^ lm) * 8)];
            #pragma unroll
            for (int c = 0; c < 4; ++c)
                #pragma unroll
                for (int i = 0; i < 4; ++i)
                    #pragma unroll
                    for (int j2 = 0; j2 < 2; ++j2)
                        acc[i][2 * h + j2] = __builtin_amdgcn_mfma_f32_16x16x32_bf16(
                            af[i][c], bfr[j2][c], acc[i][2 * h + j2], 0, 0, 0);
        }

        // row-max update (max over the 4 j-groups per row-element)
        #pragma unroll
        for (int i = 0; i < 4; ++i)
            #pragma unroll
            for (int r = 0; r < 4; ++r) {
                float m01 = fmaxf(acc[i][0][r], acc[i][1][r]);
                float m23 = fmaxf(acc[i][2][r], acc[i][3][r]);
                rv[4 * i + r] = fmaxf(rv[4 * i + r], fmaxf(m01, m23));
            }

        // col-max per j-group: in-lane tree over (i,r), then quad butterfly
        #pragma unroll
        for (int j = 0; j < 4; ++j) {
            float t0 = fmaxf(fmaxf(acc[0][j][0], acc[0][j][1]),
                             fmaxf(acc[0][j][2], acc[0][j][3]));
            float t1 = fmaxf(fmaxf(acc[1][j][0], acc[1][j][1]),
                             fmaxf(acc[1][j][2], acc[1][j][3]));
            float t2 = fmaxf(fmaxf(acc[2][j][0], acc[2][j][1]),
                             fmaxf(acc[2][j][2], acc[2][j][3]));
            float t3 = fmaxf(fmaxf(acc[3][j][0], acc[3][j][1]),
                             fmaxf(acc[3][j][2], acc[3][j][3]));
            float cv = fmaxf(fmaxf(t0, t1), fmaxf(t2, t3));
            cv = fmaxf(cv, __shfl_xor(cv, 16, 64));
            cv = fmaxf(cv, __shfl_xor(cv, 32, 64));
            if (quad == 0)   // wave-exclusive LDS row, written once per col
                colmax_lds[w][it * 64 + 16 * j + lm] = cv;
        }
    }

    // row maxes: butterfly across the 16 lane-cols; waves own disjoint rows
    // -> direct global stores, no cross-wave combine.
    #pragma unroll
    for (int s = 1; s < 16; s <<= 1)
        #pragma unroll
        for (int v = 0; v < 16; ++v)
            rv[v] = fmaxf(rv[v], __shfl_xor(rv[v], s, 64));
    if (lm == 0) {
        #pragma unroll
        for (int v = 0; v < 16; ++v)
            rowpart[((size_t)panel * B_ + b) * N_ + row0 + wrow +
                    16 * (v >> 2) + 4 * quad + (v & 3)] = rv[v];
    }

    __syncthreads();   // all colmax writes done

    // flush col partials: combine the 4 wave slices, float4 stores
    {
        const int c = tid * 4;
        float4 a0 = *(const float4*)&colmax_lds[0][c];
        float4 a1 = *(const float4*)&colmax_lds[1][c];
        float4 a2 = *(const float4*)&colmax_lds[2][c];
        float4 a3 = *(const float4*)&colmax_lds[3][c];
        float4 r;
        r.x = fmaxf(fmaxf(a0.x, a1.x), fmaxf(a2.x, a3.x));
        r.y = fmaxf(fmaxf(a0.y, a1.y), fmaxf(a2.y, a3.y));
        r.z = fmaxf(fmaxf(a0.z, a1.z), fmaxf(a2.z, a3.z));
        r.w = fmaxf(fmaxf(a0.w, a1.w), fmaxf(a2.w, a3.w));
        *(float4*)&colpart[((size_t)x * B_ + b) * M_ + (size_t)panel * 1024 + c] = r;
    }
}

// ---------------------------------------------------------------------------
// Reduce: 64 blocks (8 per batch). rows: max-e over 4 panel partials;
// cols: max-e over 16 row-block partials; d^2 = max(-2e, 0); sqrt-mean.
// ---------------------------------------------------------------------------
__global__ __launch_bounds__(256) void hausdorff_reduce(
    const float* __restrict__ rowpart, const float* __restrict__ colpart,
    float* __restrict__ out) {
    __shared__ float ws4[4];
    const int b    = blockIdx.x >> 3;
    const int part = blockIdx.x & 7;
    const int base = part * 512;
    float s = 0.f;
    for (int i = base + (int)threadIdx.x; i < base + 512; i += 256) {
        float ra = fmaxf(rowpart[((size_t)0 * B_ + b) * N_ + i],
                         rowpart[((size_t)1 * B_ + b) * N_ + i]);
        float rb = fmaxf(rowpart[((size_t)2 * B_ + b) * N_ + i],
                         rowpart[((size_t)3 * B_ + b) * N_ + i]);
        float rm = fmaxf(ra, rb);
        float ca = -1e30f, cb = -1e30f;
        #pragma unroll
        for (int xx = 0; xx < 16; xx += 2) {
            ca = fmaxf(ca, colpart[((size_t)xx * B_ + b) * M_ + i]);
            cb = fmaxf(cb, colpart[((size_t)(xx + 1) * B_ + b) * M_ + i]);
        }
        float cm = fmaxf(ca, cb);
        s += sqrtf(fmaxf(-2.f * rm, 0.f)) * (1.f / N_)
           + sqrtf(fmaxf(-2.f * cm, 0.f)) * (1.f / M_);
    }
    #pragma unroll
    for (int off = 32; off > 0; off >>= 1) s += __shfl_down(s, off, 64);
    if ((threadIdx.x & 63) == 0) ws4[threadIdx.x >> 6] = s;
    __syncthreads();
    if (threadIdx.x == 0)
        atomicAdd(&out[b], ws4[0] + ws4[1] + ws4[2] + ws4[3]);
}

extern "C" void kernel_launch(void* const* d_in, const int* in_sizes, int n_in,
                              void* d_out, int out_size, void* d_ws, size_t ws_size,
                              hipStream_t stream) {
    const float* s1 = (const float*)d_in[0];
    const float* s2 = (const float*)d_in[1];
    float* out = (float*)d_out;

    // ws: norms(BN+BM f32, pre-scaled -0.5x) | bfA | bfB |
    //     rowpart[4][B][N] | colpart[16][B][M]
    float* norms         = (float*)d_ws;
    unsigned short* bfA  = (unsigned short*)(norms + BN_ + BM_);
    unsigned short* bfB  = bfA + (size_t)BN_ * C_;
    float* rowpart       = (float*)(bfB + (size_t)BM_ * C_);
    float* colpart       = rowpart + (size_t)4 * B_ * N_;

    prep_kernel<<<(BN_ + BM_) / 16, 256, 0, stream>>>(
        s1, s2, norms, bfA, bfB, out);

    dim3 grid(N_ / 256, M_ / 1024, B_);
    hausdorff_mfma<<<grid, 256, 0, stream>>>(
        bfA, bfB, norms, norms + BN_, rowpart, colpart);

    hausdorff_reduce<<<B_ * 8, 256, 0, stream>>>(rowpart, colpart, out);
}